// Round 1
// baseline (348.229 us; speedup 1.0000x reference)
//
#include <hip/hip_runtime.h>
#include <hip/hip_bf16.h>

#define T_SEQ 80
#define EMB   100
#define HU    128
#define G4    512
#define BR    16
#define NBLK3 256
#define THR3  512

typedef __attribute__((ext_vector_type(8))) short bfrag;
typedef __attribute__((ext_vector_type(4))) float f32x4;

// ws layout (bytes)
#define OFF_EW1P 0ull                       // 10000*512*2 = 10,240,000
#define OFF_U1T  10240000ull                // 131072
#define OFF_U2T  (OFF_U1T + 131072ull)
#define OFF_W2T  (OFF_U2T + 131072ull)      // pre-swizzled

__device__ inline unsigned short f2bf(float x) {
    __hip_bfloat16 h = __float2bfloat16(x);
    unsigned short u; __builtin_memcpy(&u, &h, 2); return u;
}
__device__ inline float bf2f(unsigned short u) {
    unsigned int v = ((unsigned int)u) << 16;
    float f; __builtin_memcpy(&f, &v, 4); return f;
}
__device__ inline float sigf(float x) {
    return __builtin_amdgcn_rcpf(1.f + __expf(-x));
}
__device__ inline float tanhf_(float x) {
    x = fminf(fmaxf(x, -15.f), 15.f);
    float e = __expf(-2.f * x);
    return (1.f - e) * __builtin_amdgcn_rcpf(1.f + e);
}
// A/B frag load from swizzled row-major [rows][128] bf16 LDS tile
__device__ inline bfrag ld_frag(const unsigned short* buf, int row, int kk, int lhi) {
    int byte = (row * 256 + kk * 64 + lhi * 16) ^ ((row & 7) << 4);
    return *(const bfrag*)((const char*)buf + byte);
}
__device__ inline void st_h(unsigned short* buf, int rr, int u, unsigned short v) {
    int byte = ((rr * 256 + u * 2) ^ ((rr & 7) << 4));
    *(unsigned short*)((char*)buf + byte) = v;
}

// ---- kernel 1: transpose weights to bf16 [512][128]; W2 additionally XOR-swizzled
__global__ void prep_weights(const float* __restrict__ U1, const float* __restrict__ U2,
                             const float* __restrict__ W2,
                             unsigned short* __restrict__ U1T, unsigned short* __restrict__ U2T,
                             unsigned short* __restrict__ W2T) {
    int idx = blockIdx.x * blockDim.x + threadIdx.x;   // 0..65535
    int n = idx >> 7, k = idx & 127;
    U1T[n * 128 + k] = f2bf(U1[k * 512 + n]);
    U2T[n * 128 + k] = f2bf(U2[k * 512 + n]);
    int byte = (n * 256 + k * 2) ^ ((n & 7) << 4);
    W2T[byte >> 1] = f2bf(W2[k * 512 + n]);
}

// ---- kernel 2: EW1p[tok][u*4+g] = emb[tok]@W1[:, g*128+u] + b1  (bf16)
#define K2_TOKS 40
__global__ __launch_bounds__(512) void vocab_gemm(const float* __restrict__ emb,
                                                  const float* __restrict__ W1,
                                                  const float* __restrict__ b1,
                                                  unsigned short* __restrict__ EW1p) {
    __shared__ float embs[K2_TOKS * EMB];
    const int tid = threadIdx.x;
    const int tok0 = blockIdx.x * K2_TOKS;
    for (int i = tid; i < K2_TOKS * EMB; i += 512) embs[i] = emb[tok0 * EMB + i];
    __syncthreads();
    const int u = tid >> 2, g = tid & 3;
    const int c = g * 128 + u;
    float wcol[EMB];
#pragma unroll
    for (int e = 0; e < EMB; e++) wcol[e] = W1[e * G4 + c];
    const float bias = b1[c];
    for (int tt = 0; tt < K2_TOKS; tt++) {
        float s = bias;
#pragma unroll
        for (int e = 0; e < EMB; e++) s += embs[tt * EMB + e] * wcol[e];
        EW1p[(size_t)(tok0 + tt) * G4 + tid] = f2bf(s);
    }
}

// ---- kernel 3: fused 2-layer LSTM + dense head. 256 blocks x 512 thr, 16 rows/block.
__global__ __launch_bounds__(THR3, 2) void lstm_fused(
    const int* __restrict__ tokens, const unsigned short* __restrict__ EW1p,
    const unsigned short* __restrict__ U1T, const unsigned short* __restrict__ U2T,
    const unsigned short* __restrict__ W2T, const float* __restrict__ b2,
    const float* __restrict__ Wd, const float* __restrict__ bd, float* __restrict__ out) {

    __shared__ unsigned short w2lds[G4 * HU];      // 131072 B, swizzled
    __shared__ unsigned short h1b[2][BR * HU];     // 2 x 4 KB
    __shared__ unsigned short h2b[2][BR * HU];     // 2 x 4 KB
    __shared__ int toklds[BR * T_SEQ];             // 5 KB

    const int tid = threadIdx.x;
    const int w   = tid >> 6;
    const int l   = tid & 63;
    const int llo = l & 15, lhi = l >> 4;
    const int u   = w * 16 + llo;                  // unit 0..127 owned by this lane
    const int r0  = blockIdx.x * BR;

    { // stage pre-swizzled W2T -> LDS (linear copy)
        const uint4* src = (const uint4*)W2T;
        uint4* dst = (uint4*)w2lds;
        for (int i = tid; i < (G4 * HU * 2) / 16; i += THR3) dst[i] = src[i];
    }
    for (int i = tid; i < BR * T_SEQ; i += THR3) toklds[i] = tokens[r0 * T_SEQ + i];
    for (int i = tid; i < BR * HU; i += THR3) {
        h1b[0][i] = 0; h1b[1][i] = 0; h2b[0][i] = 0; h2b[1][i] = 0;
    }

    // U slices in registers: B-frag n = g*128 + u, k = kk*32 + lhi*8 + j
    bfrag u1s[4][4], u2s[4][4];
#pragma unroll
    for (int g = 0; g < 4; g++)
#pragma unroll
        for (int kk = 0; kk < 4; kk++) {
            size_t off = (size_t)(g * 128 + u) * 128 + kk * 32 + lhi * 8;
            u1s[g][kk] = *(const bfrag*)(U1T + off);
            u2s[g][kk] = *(const bfrag*)(U2T + off);
        }
    float bb2[4];
#pragma unroll
    for (int g = 0; g < 4; g++) bb2[g] = b2[g * 128 + u];

    float c1[4] = {0, 0, 0, 0}, c2[4] = {0, 0, 0, 0};
    __syncthreads();

    for (int t = 0; t < T_SEQ; t++) {
        const int cur = t & 1, nxt = cur ^ 1;
        unsigned short* h1cur = h1b[cur]; unsigned short* h1nxt = h1b[nxt];
        unsigned short* h2cur = h2b[cur]; unsigned short* h2nxt = h2b[nxt];

        // issue layer-1 input gathers early (EW1p holds x@W1+b1 per token)
        ushort4 zv[4];
#pragma unroll
        for (int j = 0; j < 4; j++) {
            int rr = lhi * 4 + j;
            int tok = toklds[rr * T_SEQ + t];
            zv[j] = *(const ushort4*)(EW1p + (size_t)tok * G4 + u * 4);
        }

        // ---- layer 1: acc = h1_prev @ U1
        bfrag a[4];
#pragma unroll
        for (int kk = 0; kk < 4; kk++) a[kk] = ld_frag(h1cur, llo, kk, lhi);
        f32x4 acc[4];
#pragma unroll
        for (int g = 0; g < 4; g++) acc[g] = (f32x4){0.f, 0.f, 0.f, 0.f};
#pragma unroll
        for (int g = 0; g < 4; g++)
#pragma unroll
            for (int kk = 0; kk < 4; kk++)
                acc[g] = __builtin_amdgcn_mfma_f32_16x16x32_bf16(a[kk], u1s[g][kk], acc[g], 0, 0, 0);
#pragma unroll
        for (int j = 0; j < 4; j++) {
            float zi = acc[0][j] + bf2f(zv[j].x);
            float zf = acc[1][j] + bf2f(zv[j].y);
            float zg = acc[2][j] + bf2f(zv[j].z);
            float zo = acc[3][j] + bf2f(zv[j].w);
            float cn = sigf(zf) * c1[j] + sigf(zi) * tanhf_(zg);
            c1[j] = cn;
            st_h(h1nxt, lhi * 4 + j, u, f2bf(sigf(zo) * tanhf_(cn)));
        }
        __syncthreads();   // h1[t] complete

        // ---- layer 2: acc = b2 + h1_t @ W2 + h2_prev @ U2
#pragma unroll
        for (int kk = 0; kk < 4; kk++) a[kk] = ld_frag(h1nxt, llo, kk, lhi);
#pragma unroll
        for (int g = 0; g < 4; g++) acc[g] = (f32x4){bb2[g], bb2[g], bb2[g], bb2[g]};
#pragma unroll
        for (int g = 0; g < 4; g++)
#pragma unroll
            for (int kk = 0; kk < 4; kk++) {
                bfrag bf = ld_frag(w2lds, g * 128 + u, kk, lhi);
                acc[g] = __builtin_amdgcn_mfma_f32_16x16x32_bf16(a[kk], bf, acc[g], 0, 0, 0);
            }
#pragma unroll
        for (int kk = 0; kk < 4; kk++) a[kk] = ld_frag(h2cur, llo, kk, lhi);
#pragma unroll
        for (int g = 0; g < 4; g++)
#pragma unroll
            for (int kk = 0; kk < 4; kk++)
                acc[g] = __builtin_amdgcn_mfma_f32_16x16x32_bf16(a[kk], u2s[g][kk], acc[g], 0, 0, 0);
#pragma unroll
        for (int j = 0; j < 4; j++) {
            float zi = acc[0][j], zf = acc[1][j], zg = acc[2][j], zo = acc[3][j];
            float cn = sigf(zf) * c2[j] + sigf(zi) * tanhf_(zg);
            c2[j] = cn;
            st_h(h2nxt, lhi * 4 + j, u, f2bf(sigf(zo) * tanhf_(cn)));
        }
        __syncthreads();
    }

    // ---- dense head: out = sigmoid(h2_final @ Wd + bd); final h2 is in h2b[0]
    if (w == 0) {
        int r = l >> 2, q = l & 3;
        float s = 0.f;
        for (int k = q * 32; k < q * 32 + 32; k++) {
            int byte = (r * 256 + k * 2) ^ ((r & 7) << 4);
            s += bf2f(*(const unsigned short*)((const char*)h2b[0] + byte)) * Wd[k];
        }
        s += __shfl_xor(s, 1, 64);
        s += __shfl_xor(s, 2, 64);
        if (q == 0) out[r0 + r] = sigf(s + bd[0]);
    }
}

extern "C" void kernel_launch(void* const* d_in, const int* in_sizes, int n_in,
                              void* d_out, int out_size, void* d_ws, size_t ws_size,
                              hipStream_t stream) {
    const int*   tokens = (const int*)  d_in[0];
    const float* emb    = (const float*)d_in[1];
    const float* W1     = (const float*)d_in[2];
    const float* U1     = (const float*)d_in[3];
    const float* b1     = (const float*)d_in[4];
    const float* W2     = (const float*)d_in[5];
    const float* U2     = (const float*)d_in[6];
    const float* b2     = (const float*)d_in[7];
    const float* Wd     = (const float*)d_in[8];
    const float* bd     = (const float*)d_in[9];
    float* out = (float*)d_out;

    char* ws = (char*)d_ws;
    unsigned short* EW1p = (unsigned short*)(ws + OFF_EW1P);
    unsigned short* U1T  = (unsigned short*)(ws + OFF_U1T);
    unsigned short* U2T  = (unsigned short*)(ws + OFF_U2T);
    unsigned short* W2T  = (unsigned short*)(ws + OFF_W2T);

    prep_weights<<<256, 256, 0, stream>>>(U1, U2, W2, U1T, U2T, W2T);
    vocab_gemm<<<250, 512, 0, stream>>>(emb, W1, b1, EW1p);
    lstm_fused<<<NBLK3, THR3, 0, stream>>>(tokens, EW1p, U1T, U2T, W2T, b2, Wd, bd, out);
}